// Round 2
// baseline (1040.947 us; speedup 1.0000x reference)
//
#include <hip/hip_runtime.h>
#include <hip/hip_bf16.h>

#define PI_F 3.14159265358979323846f

// ------------------------------------------------------------------
// Kernel A: three LinearOutputStacks  (latents[1024,128] -> out3[3,1024,257])
// grid (64, 3), block 256.  16 rows per block, register-blocked matmuls.
// ------------------------------------------------------------------

__device__ __forceinline__ void block_ln(float (*buf)[256], float* mrow, float* rrow)
{
    const int tid = threadIdx.x;
    const int lane = tid & 63, wv = tid >> 6;
    for (int r = wv; r < 16; r += 4) {
        float s = 0.f, s2 = 0.f;
        #pragma unroll
        for (int j = 0; j < 4; j++) {
            float v = buf[r][lane + 64*j];
            s += v; s2 += v*v;
        }
        #pragma unroll
        for (int o = 32; o > 0; o >>= 1) {
            s  += __shfl_xor(s,  o, 64);
            s2 += __shfl_xor(s2, o, 64);
        }
        if (lane == 0) {
            float m   = s * (1.f/256.f);
            float var = s2 * (1.f/256.f) - m*m;
            mrow[r] = m;
            rrow[r] = rsqrtf(var + 1e-5f);
        }
    }
    __syncthreads();
    #pragma unroll
    for (int r = 0; r < 16; r++)
        buf[r][tid] = (buf[r][tid] - mrow[r]) * rrow[r];
    __syncthreads();
}

// 256->256 matmul + bias + leaky_relu(0.2), in -> outb
__device__ __forceinline__ void mm256(const float (*in)[256], const float* __restrict__ W,
                                      const float* __restrict__ bias, float (*outb)[256])
{
    const int tid = threadIdx.x;
    float acc[16];
    #pragma unroll
    for (int r = 0; r < 16; r++) acc[r] = 0.f;
    const float* Wp = W + tid;
    for (int l = 0; l < 256; l++) {
        float w = Wp[l*256];
        #pragma unroll
        for (int r = 0; r < 16; r++) acc[r] = fmaf(in[r][l], w, acc[r]);
    }
    const float bb = bias[tid];
    #pragma unroll
    for (int r = 0; r < 16; r++) {
        float v = acc[r] + bb;
        outb[r][tid] = (v >= 0.f) ? v : 0.2f*v;
    }
}

__global__ __launch_bounds__(256) void mlp_kernel(
    const float* __restrict__ latents,
    const float* __restrict__ Win,  const float* __restrict__ b_in,
    const float* __restrict__ Wh,   const float* __restrict__ b_h,
    const float* __restrict__ Wout, const float* __restrict__ b_out,
    float* __restrict__ out3)
{
    __shared__ float bufA[16][128];
    __shared__ float bufB[16][256];
    __shared__ float bufC[16][256];
    __shared__ float mrow[16], rrow[16];

    const int tid  = threadIdx.x;
    const int s    = blockIdx.y;
    const int row0 = blockIdx.x * 16;

    for (int idx = tid; idx < 16*128; idx += 256) {
        int r = idx >> 7, l = idx & 127;
        bufA[r][l] = latents[(size_t)(row0 + r)*128 + l];
    }
    __syncthreads();

    // layer 1: 128 -> 256 (+bias, lrelu)
    {
        float acc[16];
        #pragma unroll
        for (int r = 0; r < 16; r++) acc[r] = 0.f;
        const float* Wp = Win + (size_t)s*128*256 + tid;
        for (int l = 0; l < 128; l++) {
            float w = Wp[l*256];
            #pragma unroll
            for (int r = 0; r < 16; r++) acc[r] = fmaf(bufA[r][l], w, acc[r]);
        }
        const float bias = b_in[s*256 + tid];
        #pragma unroll
        for (int r = 0; r < 16; r++) {
            float v = acc[r] + bias;
            bufB[r][tid] = (v >= 0.f) ? v : 0.2f*v;
        }
    }
    __syncthreads();
    block_ln(bufB, mrow, rrow);

    // hidden 1
    mm256(bufB, Wh + ((size_t)s*2 + 0)*256*256, b_h + (s*2 + 0)*256, bufC);
    __syncthreads();
    block_ln(bufC, mrow, rrow);

    // hidden 2
    mm256(bufC, Wh + ((size_t)s*2 + 1)*256*256, b_h + (s*2 + 1)*256, bufB);
    __syncthreads();
    block_ln(bufB, mrow, rrow);

    // output layer: 256 -> 257 (+bias), raw, to out3
    for (int pass = 0; pass < 2; ++pass) {
        int n = tid + pass*256;
        if (n < 257) {
            float acc[16];
            #pragma unroll
            for (int r = 0; r < 16; r++) acc[r] = 0.f;
            const float* Wp = Wout + (size_t)s*256*257 + n;
            for (int l = 0; l < 256; l++) {
                float w = Wp[l*257];
                #pragma unroll
                for (int r = 0; r < 16; r++) acc[r] = fmaf(bufB[r][l], w, acc[r]);
            }
            float bb = b_out[s*257 + n];
            for (int r = 0; r < 16; r++)
                out3[((size_t)s*1024 + row0 + r)*257 + n] = acc[r] + bb;
        }
    }
}

// ------------------------------------------------------------------
// Kernel B: fused resonance decay + phase cumsum + iDFT + Hann + OLA
// grid 1024 (one block per (b,e)), block 256.
// Thread tid owns spectral bin k=tid (thread 0 also owns k=256) for the
// sequential state, and owns output columns w=tid / w=tid+256 for the DFT.
// x[w]      = sum_k  a_k cos(2pi k w/512) + b_k sin(2pi k w/512) = xe + xo
// x[w+256]  = sum_k (-1)^k (...)                                 = xe - xo
// ------------------------------------------------------------------

#define ACC8(dst, kidx, cc) do { \
    float4 p0 = abp[(kidx)*4+0]; \
    float4 p1 = abp[(kidx)*4+1]; \
    float4 p2 = abp[(kidx)*4+2]; \
    float4 p3 = abp[(kidx)*4+3]; \
    dst[0] = fmaf(p0.x, cc.x, fmaf(p0.y, cc.y, dst[0])); \
    dst[1] = fmaf(p0.z, cc.x, fmaf(p0.w, cc.y, dst[1])); \
    dst[2] = fmaf(p1.x, cc.x, fmaf(p1.y, cc.y, dst[2])); \
    dst[3] = fmaf(p1.z, cc.x, fmaf(p1.w, cc.y, dst[3])); \
    dst[4] = fmaf(p2.x, cc.x, fmaf(p2.y, cc.y, dst[4])); \
    dst[5] = fmaf(p2.z, cc.x, fmaf(p2.w, cc.y, dst[5])); \
    dst[6] = fmaf(p3.x, cc.x, fmaf(p3.y, cc.y, dst[6])); \
    dst[7] = fmaf(p3.z, cc.x, fmaf(p3.w, cc.y, dst[7])); \
} while (0)

__global__ __launch_bounds__(256) void synth_kernel(
    const float* __restrict__ out3,
    const float* __restrict__ phase0_u,
    const float* __restrict__ noise_u,
    float* __restrict__ out)
{
    __shared__ float2 ctab[512];
    __shared__ __align__(16) float ab[257*16];   // [k][frame(8)][a,b]

    const int tid = threadIdx.x;
    const int row = blockIdx.x;          // b*512 + e
    const int b   = row >> 9;
    const int e   = row & 511;

    for (int j = tid; j < 512; j += 256) {
        float sn, cn;
        sincosf((2.f*PI_F/512.f) * (float)j, &sn, &cn);
        ctab[j] = make_float2(cn, sn);
    }

    const float inv = 0.04419417382415922f;   // 1/sqrt(512)

    // per-thread sequential state for k = tid
    float initial_a = out3[((size_t)0*1024 + row)*257 + tid];
    float respre_a  = out3[((size_t)1*1024 + row)*257 + tid];
    float dithpre_a = out3[((size_t)2*1024 + row)*257 + tid];
    float res_a  = 0.5f + 0.4995f / (1.f + expf(-respre_a));
    float dith_a = 1.f / (1.f + expf(-dithpre_a));
    float pha_a  = (phase0_u[(size_t)row*257 + tid]*2.f - 1.f) * PI_F;
    float mag_a  = initial_a;
    const float gd_a = PI_F * (float)tid * (1.f/256.f);
    const float cs_a = (tid == 0 ? 1.f : 2.f) * inv;

    // thread 0 additionally owns k = 256
    float res_b = 1.f, dith_b = 0.f, pha_b = 0.f, mag_b = 0.f;
    if (tid == 0) {
        float i2 = out3[((size_t)0*1024 + row)*257 + 256];
        float r2 = out3[((size_t)1*1024 + row)*257 + 256];
        float d2 = out3[((size_t)2*1024 + row)*257 + 256];
        res_b  = 0.5f + 0.4995f / (1.f + expf(-r2));
        dith_b = 1.f / (1.f + expf(-d2));
        pha_b  = (phase0_u[(size_t)row*257 + 256]*2.f - 1.f) * PI_F;
        mag_b  = i2;
    }
    const float cs_b = inv;
    const float gd_b = PI_F;

    __syncthreads();

    const int w = tid;
    float wn1, wn2;
    {
        float c0 = ctab[tid].x;            // cos(2*pi*tid/512)
        wn1 = 0.5f - 0.5f*c0;              // hann(tid)
        wn2 = 0.5f + 0.5f*c0;              // hann(tid+256)
    }

    const float* nrow = noise_u + ((size_t)b*128*512 + e)*257;
    const size_t nstride = (size_t)512*257;

    float tail = 0.f;
    const float4* abp = (const float4*)ab;

    for (int g = 0; g < 16; ++g) {
        // ---- phase 1: coefficients for 8 frames ----
        for (int f = 0; f < 8; ++f) {
            const int t = g*8 + f;
            if (t > 0) {
                float nz = (nrow[(size_t)t*nstride + tid]*2.f - 1.f) * PI_F;
                mag_a *= res_a;
                pha_a += gd_a + dith_a*nz;
            }
            float sn, cn;
            sincosf(pha_a, &sn, &cn);
            float am = cs_a * mag_a;
            ab[tid*16 + 2*f    ] =  am * cn;
            ab[tid*16 + 2*f + 1] = -am * sn;
            if (tid == 0) {
                if (t > 0) {
                    float nz = (nrow[(size_t)t*nstride + 256]*2.f - 1.f) * PI_F;
                    mag_b *= res_b;
                    pha_b += gd_b + dith_b*nz;
                }
                float sn2, cn2;
                sincosf(pha_b, &sn2, &cn2);
                float am2 = cs_b * mag_b;
                ab[256*16 + 2*f    ] =  am2 * cn2;
                ab[256*16 + 2*f + 1] = -am2 * sn2;
            }
        }
        __syncthreads();

        // ---- phase 2: iDFT accumulation over k ----
        float xe[8], xo[8];
        #pragma unroll
        for (int f = 0; f < 8; f++) { xe[f] = 0.f; xo[f] = 0.f; }
        int idx = 0;                                   // (k*w) & 511
        #pragma unroll 4
        for (int kk = 0; kk < 256; kk += 2) {
            float2 c0 = ctab[idx]; idx = (idx + w) & 511;
            ACC8(xe, kk, c0);
            float2 c1 = ctab[idx]; idx = (idx + w) & 511;
            ACC8(xo, kk + 1, c1);
        }
        {
            float2 cL = ctab[idx];                     // k = 256
            ACC8(xe, 256, cL);
        }
        __syncthreads();

        // ---- phase 3: Hann window + streaming overlap-add ----
        #pragma unroll
        for (int f = 0; f < 8; ++f) {
            const int t = g*8 + f;
            float x1 = xe[f] + xo[f];                  // x[tid]
            float x2 = xe[f] - xo[f];                  // x[tid+256]
            float val = fmaf(x1, wn1, tail);
            tail = x2 * wn2;                           // carried to next frame
            out[(size_t)row*32768 + (size_t)t*256 + tid] = val;
        }
        // (tail of t=127 is dropped: matches out[..., :RS] truncation)
    }
}

// ------------------------------------------------------------------

extern "C" void kernel_launch(void* const* d_in, const int* in_sizes, int n_in,
                              void* d_out, int out_size, void* d_ws, size_t ws_size,
                              hipStream_t stream)
{
    const float* latents  = (const float*)d_in[0];
    const float* phase0_u = (const float*)d_in[1];
    const float* noise_u  = (const float*)d_in[2];
    const float* Win      = (const float*)d_in[3];
    const float* b_in     = (const float*)d_in[4];
    const float* Wh       = (const float*)d_in[5];
    const float* b_h      = (const float*)d_in[6];
    const float* Wout     = (const float*)d_in[7];
    const float* b_out    = (const float*)d_in[8];

    float* out3 = (float*)d_ws;                       // [3][1024][257] fp32, ~3.2 MB
    float* out  = (float*)d_out;                      // [2][512][32768] fp32

    dim3 gA(64, 3);
    mlp_kernel<<<gA, 256, 0, stream>>>(latents, Win, b_in, Wh, b_h, Wout, b_out, out3);
    synth_kernel<<<1024, 256, 0, stream>>>(out3, phase0_u, noise_u, out);
}

// Round 3
// 622.308 us; speedup vs baseline: 1.6727x; 1.6727x over previous
//
#include <hip/hip_runtime.h>
#include <hip/hip_bf16.h>

#define PI_F 3.14159265358979323846f

typedef short  bf16x8 __attribute__((ext_vector_type(8)));
typedef unsigned short u16x8 __attribute__((ext_vector_type(8)));
typedef float  f32x4  __attribute__((ext_vector_type(4)));

// ---- ws layout (bytes) ----
#define OUT3_OFF  0                       // [3][1024][257] f32 = 3,158,016 B
#define TPACK_OFF 3158016                 // [544 tiles][64][8] bf16 = 557,056 B
#define TAIL_OFF  (3158016 + 557056)      // [1024][4][256] f32 = 4,194,304 B

static __device__ __forceinline__ unsigned short f2bf(float x) {
    unsigned int u = __float_as_uint(x);
    unsigned int r = (u + 0x7fffu + ((u >> 16) & 1u)) >> 16;   // RNE
    return (unsigned short)r;
}

// ------------------------------------------------------------------
// Kernel A: three LinearOutputStacks (unchanged from round 2)
// ------------------------------------------------------------------

__device__ __forceinline__ void block_ln(float (*buf)[256], float* mrow, float* rrow)
{
    const int tid = threadIdx.x;
    const int lane = tid & 63, wv = tid >> 6;
    for (int r = wv; r < 16; r += 4) {
        float s = 0.f, s2 = 0.f;
        #pragma unroll
        for (int j = 0; j < 4; j++) {
            float v = buf[r][lane + 64*j];
            s += v; s2 += v*v;
        }
        #pragma unroll
        for (int o = 32; o > 0; o >>= 1) {
            s  += __shfl_xor(s,  o, 64);
            s2 += __shfl_xor(s2, o, 64);
        }
        if (lane == 0) {
            float m   = s * (1.f/256.f);
            float var = s2 * (1.f/256.f) - m*m;
            mrow[r] = m;
            rrow[r] = rsqrtf(var + 1e-5f);
        }
    }
    __syncthreads();
    #pragma unroll
    for (int r = 0; r < 16; r++)
        buf[r][tid] = (buf[r][tid] - mrow[r]) * rrow[r];
    __syncthreads();
}

__device__ __forceinline__ void mm256(const float (*in)[256], const float* __restrict__ W,
                                      const float* __restrict__ bias, float (*outb)[256])
{
    const int tid = threadIdx.x;
    float acc[16];
    #pragma unroll
    for (int r = 0; r < 16; r++) acc[r] = 0.f;
    const float* Wp = W + tid;
    for (int l = 0; l < 256; l++) {
        float w = Wp[l*256];
        #pragma unroll
        for (int r = 0; r < 16; r++) acc[r] = fmaf(in[r][l], w, acc[r]);
    }
    const float bb = bias[tid];
    #pragma unroll
    for (int r = 0; r < 16; r++) {
        float v = acc[r] + bb;
        outb[r][tid] = (v >= 0.f) ? v : 0.2f*v;
    }
}

__global__ __launch_bounds__(256) void mlp_kernel(
    const float* __restrict__ latents,
    const float* __restrict__ Win,  const float* __restrict__ b_in,
    const float* __restrict__ Wh,   const float* __restrict__ b_h,
    const float* __restrict__ Wout, const float* __restrict__ b_out,
    float* __restrict__ out3)
{
    __shared__ float bufA[16][128];
    __shared__ float bufB[16][256];
    __shared__ float bufC[16][256];
    __shared__ float mrow[16], rrow[16];

    const int tid  = threadIdx.x;
    const int s    = blockIdx.y;
    const int row0 = blockIdx.x * 16;

    for (int idx = tid; idx < 16*128; idx += 256) {
        int r = idx >> 7, l = idx & 127;
        bufA[r][l] = latents[(size_t)(row0 + r)*128 + l];
    }
    __syncthreads();

    {
        float acc[16];
        #pragma unroll
        for (int r = 0; r < 16; r++) acc[r] = 0.f;
        const float* Wp = Win + (size_t)s*128*256 + tid;
        for (int l = 0; l < 128; l++) {
            float w = Wp[l*256];
            #pragma unroll
            for (int r = 0; r < 16; r++) acc[r] = fmaf(bufA[r][l], w, acc[r]);
        }
        const float bias = b_in[s*256 + tid];
        #pragma unroll
        for (int r = 0; r < 16; r++) {
            float v = acc[r] + bias;
            bufB[r][tid] = (v >= 0.f) ? v : 0.2f*v;
        }
    }
    __syncthreads();
    block_ln(bufB, mrow, rrow);

    mm256(bufB, Wh + ((size_t)s*2 + 0)*256*256, b_h + (s*2 + 0)*256, bufC);
    __syncthreads();
    block_ln(bufC, mrow, rrow);

    mm256(bufC, Wh + ((size_t)s*2 + 1)*256*256, b_h + (s*2 + 1)*256, bufB);
    __syncthreads();
    block_ln(bufB, mrow, rrow);

    for (int pass = 0; pass < 2; ++pass) {
        int n = tid + pass*256;
        if (n < 257) {
            float acc[16];
            #pragma unroll
            for (int r = 0; r < 16; r++) acc[r] = 0.f;
            const float* Wp = Wout + (size_t)s*256*257 + n;
            for (int l = 0; l < 256; l++) {
                float w = Wp[l*257];
                #pragma unroll
                for (int r = 0; r < 16; r++) acc[r] = fmaf(bufB[r][l], w, acc[r]);
            }
            float bb = b_out[s*257 + n];
            for (int r = 0; r < 16; r++)
                out3[((size_t)s*1024 + row0 + r)*257 + n] = acc[r] + bb;
        }
    }
}

// ------------------------------------------------------------------
// K1: pack the iDFT basis T[k2][w] (bf16) in MFMA B-fragment order.
//  k2 = 2k   -> cos(2*pi*k*w/512)
//  k2 = 2k+1 -> sin(2*pi*k*w/512)      (k2 >= 514 zero-padded)
// B-frag for 16x16x32: lane l holds B[k2 = ks*32+(l>>4)*8+j][w = nt*16+(l&15)]
// tile index = ks*32 + nt;  elem addr = (tile*64 + l)*8 + j
// ------------------------------------------------------------------
__global__ __launch_bounds__(256) void tpack_init(unsigned short* __restrict__ tp)
{
    int g = blockIdx.x * 256 + threadIdx.x;      // 544*64 = 34816 threads exactly
    int tile = g >> 6, l = g & 63;
    int ks = tile >> 5, nt = tile & 31;
    u16x8 v;
    #pragma unroll
    for (int j = 0; j < 8; ++j) {
        int k2 = ks*32 + ((l >> 4) << 3) + j;
        int w  = nt*16 + (l & 15);
        float val = 0.f;
        if (k2 < 514) {
            int kk = k2 >> 1;
            int m  = (kk * w) & 511;             // exact angle reduction
            float ang = (float)m * (PI_F / 256.f);
            float sn, cn; sincosf(ang, &sn, &cn);
            val = (k2 & 1) ? sn : cn;
        }
        v[j] = f2bf(val);
    }
    *(u16x8*)(tp + (size_t)g * 8) = v;
}

// ------------------------------------------------------------------
// K2: fused AB generation + MFMA iDFT + Hann/OLA.
// grid 4096 = (row = b*512+e) * 4 frame-chunks of 32; block 256 (4 waves).
// LDS union: phase1/2: abt u32[32][276]  (bf16 pairs (a,b) per k)
//            phase3:   xb  f32[512][36]
// ------------------------------------------------------------------
__global__ __launch_bounds__(256) void synth_mfma(
    const float* __restrict__ out3,
    const float* __restrict__ phase0_u,
    const float* __restrict__ noise_u,
    const unsigned short* __restrict__ tpack,
    float* __restrict__ tail_buf,
    float* __restrict__ out)
{
    __shared__ __align__(16) unsigned char lds_raw[73728];
    unsigned int* abt = (unsigned int*)lds_raw;     // [32][276]
    float*        xb  = (float*)lds_raw;            // [512][36]

    const int tid = threadIdx.x;
    const int bx  = blockIdx.x;
    const int row = bx >> 2;
    const int fc  = bx & 3;
    const int b   = row >> 9;
    const int e   = row & 511;

    // zero the K-padding columns (u32 cols 257..275) once
    for (int i = tid; i < 32*19; i += 256) {
        int r = i / 19, c = 257 + i % 19;
        abt[r*276 + c] = 0;
    }

    // ---- phase 1: sequential state + AB coefficients for this chunk ----
    const int k = tid;
    const float inv = 0.04419417382415922f;        // 1/sqrt(512)

    float ini  = out3[((size_t)0*1024 + row)*257 + k];
    float rpre = out3[((size_t)1*1024 + row)*257 + k];
    float dpre = out3[((size_t)2*1024 + row)*257 + k];
    float res  = 0.5f + 0.4995f / (1.f + expf(-rpre));
    float dith = 1.f / (1.f + expf(-dpre));
    float pha  = (phase0_u[(size_t)row*257 + k]*2.f - 1.f) * PI_F;
    float mag  = ini;
    const float gd = PI_F * (float)k * (1.f/256.f);
    const float cs = (k == 0 ? 1.f : 2.f) * inv;

    float res2=1.f, dith2=0.f, pha2=0.f, mag2=0.f;  // bin 256 on thread 0
    if (tid == 0) {
        float i2 = out3[((size_t)0*1024 + row)*257 + 256];
        float r2 = out3[((size_t)1*1024 + row)*257 + 256];
        float d2 = out3[((size_t)2*1024 + row)*257 + 256];
        res2  = 0.5f + 0.4995f / (1.f + expf(-r2));
        dith2 = 1.f / (1.f + expf(-d2));
        pha2  = (phase0_u[(size_t)row*257 + 256]*2.f - 1.f) * PI_F;
        mag2  = i2;
    }

    const float* nrow = noise_u + ((size_t)b*128*512 + e)*257;
    const size_t nstride = (size_t)512*257;
    const int t1 = fc * 32;

    // prefix scan: advance state through frames [1, t1)
    for (int t = 1; t < t1; ++t) {
        float nz = (nrow[(size_t)t*nstride + k]*2.f - 1.f) * PI_F;
        mag *= res;
        pha += gd + dith*nz;
        if (tid == 0) {
            float nz2 = (nrow[(size_t)t*nstride + 256]*2.f - 1.f) * PI_F;
            mag2 *= res2;
            pha2 += PI_F + dith2*nz2;
        }
    }

    // this chunk's 32 frames -> bf16 (a,b) pairs in LDS
    for (int f = 0; f < 32; ++f) {
        const int t = t1 + f;
        if (t > 0) {
            float nz = (nrow[(size_t)t*nstride + k]*2.f - 1.f) * PI_F;
            mag *= res;
            pha += gd + dith*nz;
        }
        float sn, cn; sincosf(pha, &sn, &cn);
        float am = cs * mag;
        abt[f*276 + k] = (unsigned int)f2bf(am*cn) | ((unsigned int)f2bf(-am*sn) << 16);
        if (tid == 0) {
            if (t > 0) {
                float nz2 = (nrow[(size_t)t*nstride + 256]*2.f - 1.f) * PI_F;
                mag2 *= res2;
                pha2 += PI_F + dith2*nz2;
            }
            float sn2, cn2; sincosf(pha2, &sn2, &cn2);
            float am2 = inv * mag2;
            abt[f*276 + 256] = (unsigned int)f2bf(am2*cn2) | ((unsigned int)f2bf(-am2*sn2) << 16);
        }
    }
    __syncthreads();

    // ---- phase 2: MFMA  X[f][w] = AB^T[f][k2] * T[k2][w] ----
    const int l  = tid & 63;
    const int wv = tid >> 6;

    f32x4 acc[2][8];
    #pragma unroll
    for (int mt = 0; mt < 2; ++mt)
        #pragma unroll
        for (int nt = 0; nt < 8; ++nt)
            acc[mt][nt] = (f32x4){0.f, 0.f, 0.f, 0.f};

    const int4* abt4 = (const int4*)lds_raw;        // [32][69] int4
    const int4* Tp   = (const int4*)tpack;
    const int a_col  = (l >> 4);                    // int4 col within k-step
    const int r0     = (l & 15) * 69;
    const int r1     = ((l & 15) + 16) * 69;

    for (int ks = 0; ks < 17; ++ks) {
        int4 a0i = abt4[r0 + ks*4 + a_col];
        int4 a1i = abt4[r1 + ks*4 + a_col];
        bf16x8 A0 = *(bf16x8*)&a0i;
        bf16x8 A1 = *(bf16x8*)&a1i;
        const int4* tb = Tp + (size_t)(ks*32 + wv*8)*64 + l;
        #pragma unroll
        for (int nt = 0; nt < 8; ++nt) {
            int4 bi = tb[nt*64];
            bf16x8 B = *(bf16x8*)&bi;
            acc[0][nt] = __builtin_amdgcn_mfma_f32_16x16x32_bf16(A0, B, acc[0][nt], 0, 0, 0);
            acc[1][nt] = __builtin_amdgcn_mfma_f32_16x16x32_bf16(A1, B, acc[1][nt], 0, 0, 0);
        }
    }
    __syncthreads();   // all ABt reads done before xb overwrites the union

    // ---- phase 3: acc -> LDS X[w][36], then Hann + OLA + store ----
    #pragma unroll
    for (int mt = 0; mt < 2; ++mt)
        #pragma unroll
        for (int nt = 0; nt < 8; ++nt) {
            int w     = wv*128 + nt*16 + (l & 15);
            int fbase = mt*16 + ((l >> 4) << 2);
            *(f32x4*)(&xb[w*36 + fbase]) = acc[mt][nt];
        }
    __syncthreads();

    {
        float c0 = cosf((float)tid * (PI_F/256.f));
        float h1 = 0.5f - 0.5f*c0;                  // hann[tid]
        float h2 = 0.5f + 0.5f*c0;                  // hann[tid+256]
        float tail = 0.f;
        const f32x4* xA = (const f32x4*)&xb[tid*36];
        const f32x4* xB = (const f32x4*)&xb[(tid + 256)*36];
        float* orow = out + (size_t)row*32768 + (size_t)fc*8192 + tid;
        #pragma unroll
        for (int q = 0; q < 8; ++q) {
            f32x4 xa = xA[q];
            f32x4 xv = xB[q];
            #pragma unroll
            for (int r = 0; r < 4; ++r) {
                float v = fmaf(xa[r], h1, tail);
                tail = xv[r] * h2;
                orow[(q*4 + r)*256] = v;
            }
        }
        tail_buf[((size_t)row*4 + fc)*256 + tid] = tail;
    }
}

// ------------------------------------------------------------------
// K3: add the cross-chunk OLA tail into the first frame of chunks 1..3
// ------------------------------------------------------------------
__global__ __launch_bounds__(256) void tail_add(
    const float* __restrict__ tail_buf, float* __restrict__ out)
{
    int bx = blockIdx.x;                 // 1024*3
    int row = bx / 3, j = bx % 3;        // chunk fc = j+1
    int tid = threadIdx.x;
    out[(size_t)row*32768 + (size_t)(j + 1)*8192 + tid] +=
        tail_buf[((size_t)row*4 + j)*256 + tid];
}

// ------------------------------------------------------------------

extern "C" void kernel_launch(void* const* d_in, const int* in_sizes, int n_in,
                              void* d_out, int out_size, void* d_ws, size_t ws_size,
                              hipStream_t stream)
{
    const float* latents  = (const float*)d_in[0];
    const float* phase0_u = (const float*)d_in[1];
    const float* noise_u  = (const float*)d_in[2];
    const float* Win      = (const float*)d_in[3];
    const float* b_in     = (const float*)d_in[4];
    const float* Wh       = (const float*)d_in[5];
    const float* b_h      = (const float*)d_in[6];
    const float* Wout     = (const float*)d_in[7];
    const float* b_out    = (const float*)d_in[8];

    unsigned char* ws = (unsigned char*)d_ws;
    float*          out3  = (float*)(ws + OUT3_OFF);
    unsigned short* tpack = (unsigned short*)(ws + TPACK_OFF);
    float*          tailb = (float*)(ws + TAIL_OFF);
    float*          out   = (float*)d_out;

    dim3 gA(64, 3);
    mlp_kernel<<<gA, 256, 0, stream>>>(latents, Win, b_in, Wh, b_h, Wout, b_out, out3);
    tpack_init<<<136, 256, 0, stream>>>(tpack);
    synth_mfma<<<4096, 256, 0, stream>>>(out3, phase0_u, noise_u, tpack, tailb, out);
    tail_add<<<3072, 256, 0, stream>>>(tailb, out);
}